// Round 19
// baseline (743.347 us; speedup 1.0000x reference)
//
#include <hip/hip_runtime.h>

typedef __attribute__((ext_vector_type(8))) short bf16x8;
typedef __attribute__((ext_vector_type(8))) unsigned short ushort8_t;
typedef __attribute__((ext_vector_type(4))) float f32x4;
typedef __attribute__((ext_vector_type(16))) float f32x16;

#define NB 16384
#define NK 2048
#define ND 1000
#define KP 1024            // padded K
#define NCHK 1024          // sinkhorn partial chunks (1 per sweep block)

__device__ ushort g_E[(size_t)NB * NK];             // 64 MiB fp16 e' = exp(-2d)*8192 (hi)
__device__ ushort g_R[(size_t)NB * NK];             // 64 MiB fp16 residual (e32 - hi)
__device__ ushort g_Fh[(size_t)NB * KP], g_Fl[(size_t)NB * KP];   // pre-swizzled (64k windows)
__device__ ushort g_Ch[(size_t)NK * KP], g_Cl[(size_t)NK * KP];
__device__ float  g_u[NK], g_c2[NK];
__device__ float  g_f2[NB], g_bd[NB];
__device__ float  g_part[(size_t)NCHK * NK];        // 8 MiB
__device__ int    g_cc[NK], g_rc[NK];

typedef const __attribute__((address_space(1))) void gvoid_t;
typedef __attribute__((address_space(3))) void lvoid_t;

union h16 { ushort u; _Float16 h; };

__device__ __forceinline__ ushort bf16_rne(float x){
    uint u = __float_as_uint(x);
    uint lsb = (u >> 16) & 1u;
    u += 0x7fffu + lsb;
    return (ushort)(u >> 16);
}
__device__ __forceinline__ float bf16_to_f(ushort h){
    return __uint_as_float(((uint)h) << 16);
}

// ---------------- prep (merged): fp32 -> (hi,lo) bf16 split, K-pad, row-sumsq ----------------
__global__ __launch_bounds__(256) void cn_prep(const float* __restrict__ F,
                                               const float* __restrict__ Cn){
    const int isC = (blockIdx.x >= NB);
    const int row = isC ? (blockIdx.x - NB) : blockIdx.x;
    const float* __restrict__ X = isC ? Cn : F;
    ushort* __restrict__ H = isC ? g_Ch : g_Fh;
    ushort* __restrict__ L = isC ? g_Cl : g_Fl;
    float*  __restrict__ sq = isC ? g_c2 : g_f2;
    const int t = threadIdx.x;
    const int lane = t & 63, wid = t >> 6;
    if (isC && t == 0){ g_cc[row] = 0; g_rc[row] = 0; }
    float4 x = make_float4(0.f,0.f,0.f,0.f);
    if (t < 250) x = *(const float4*)(X + (size_t)row * ND + 4 * t);
    double s = (double)x.x*x.x + (double)x.y*x.y + (double)x.z*x.z + (double)x.w*x.w;
    ushort4 h4, l4;
#pragma unroll
    for (int c = 0; c < 4; ++c){
        float xc = (&x.x)[c];
        ushort h = bf16_rne(xc);
        (&h4.x)[c] = h;
        (&l4.x)[c] = bf16_rne(xc - bf16_to_f(h));
    }
    const int base = (t >> 4) << 6;                 // 64-col window
    const int grp  = (t >> 1) & 7;                  // granule 0..7 within window
    const int pos  = base + ((grp ^ (row & 7)) << 3) + ((4 * t) & 7);
    *(ushort4*)&H[(size_t)row * KP + pos] = h4;
    *(ushort4*)&L[(size_t)row * KP + pos] = l4;

    __shared__ double pr[4];
    for (int off = 32; off; off >>= 1) s += __shfl_xor(s, off);
    if (lane == 0) pr[wid] = s;
    __syncthreads();
    if (t == 0) sq[row] = (float)(pr[0] + pr[1] + pr[2] + pr[3]);
}

// ---------------- split-bf16 32x32x16 MFMA distance GEMM, BK=64 single-buffer ----------------
// + T1 XCD-aware block swizzle (bijective: 2048 % 8 == 0).
__global__ __launch_bounds__(256) void cn_gemm_dist(){
    __shared__ __attribute__((aligned(16))) ushort Ah[128 * 64];
    __shared__ __attribute__((aligned(16))) ushort Al[128 * 64];
    __shared__ __attribute__((aligned(16))) ushort Bh[128 * 64];
    __shared__ __attribute__((aligned(16))) ushort Bl[128 * 64];

    const int tid = threadIdx.x;
    const int lane = tid & 63, wid = tid >> 6;
    const int wr = wid >> 1, wc = wid & 1;

    const int lin = blockIdx.y * gridDim.x + blockIdx.x;
    const int swz = (lin & 7) * 256 + (lin >> 3);
    const int brow0 = (swz >> 4) * 128;
    const int bcol0 = (swz & 15) * 128;

    f32x16 acc[2][2];
#pragma unroll
    for (int mt = 0; mt < 2; ++mt)
#pragma unroll
        for (int nt = 0; nt < 2; ++nt)
#pragma unroll
            for (int r = 0; r < 16; ++r) acc[mt][nt][r] = 0.f;

    const int srow = lane >> 3;
    const int sgr  = lane & 7;

    const int arow = wr * 64 + (lane & 31);
    const int brow = wc * 64 + (lane & 31);
    const int kh   = lane >> 5;
    const int rx   = lane & 7;

    for (int kt = 0; kt < 16; ++kt){
        const int k0 = kt * 64;
#pragma unroll
        for (int c4 = 0; c4 < 4; ++c4){
            const int ch = wid * 4 + c4;
            const int ldso = ch * 512;
            const size_t ga = (size_t)(brow0 + ch * 8 + srow) * KP + k0 + sgr * 8;
            const size_t gb = (size_t)(bcol0 + ch * 8 + srow) * KP + k0 + sgr * 8;
            __builtin_amdgcn_global_load_lds((gvoid_t*)(g_Fh + ga), (lvoid_t*)(Ah + ldso), 16, 0, 0);
            __builtin_amdgcn_global_load_lds((gvoid_t*)(g_Fl + ga), (lvoid_t*)(Al + ldso), 16, 0, 0);
            __builtin_amdgcn_global_load_lds((gvoid_t*)(g_Ch + gb), (lvoid_t*)(Bh + ldso), 16, 0, 0);
            __builtin_amdgcn_global_load_lds((gvoid_t*)(g_Cl + gb), (lvoid_t*)(Bl + ldso), 16, 0, 0);
        }
        __syncthreads();

#pragma unroll
        for (int ks = 0; ks < 4; ++ks){
            const int pg = (ks * 2 + kh) ^ rx;
            bf16x8 a_h[2], a_l[2], b_h[2], b_l[2];
#pragma unroll
            for (int mt = 0; mt < 2; ++mt){
                const int ro = (arow + mt * 32) * 64 + pg * 8;
                a_h[mt] = *(const bf16x8*)&Ah[ro];
                a_l[mt] = *(const bf16x8*)&Al[ro];
            }
#pragma unroll
            for (int nt = 0; nt < 2; ++nt){
                const int ro = (brow + nt * 32) * 64 + pg * 8;
                b_h[nt] = *(const bf16x8*)&Bh[ro];
                b_l[nt] = *(const bf16x8*)&Bl[ro];
            }
#pragma unroll
            for (int mt = 0; mt < 2; ++mt)
#pragma unroll
                for (int nt = 0; nt < 2; ++nt){
                    acc[mt][nt] = __builtin_amdgcn_mfma_f32_32x32x16_bf16(a_h[mt], b_h[nt], acc[mt][nt], 0, 0, 0);
                    acc[mt][nt] = __builtin_amdgcn_mfma_f32_32x32x16_bf16(a_h[mt], b_l[nt], acc[mt][nt], 0, 0, 0);
                    acc[mt][nt] = __builtin_amdgcn_mfma_f32_32x32x16_bf16(a_l[mt], b_h[nt], acc[mt][nt], 0, 0, 0);
                }
        }
        __syncthreads();
    }

#pragma unroll
    for (int mt = 0; mt < 2; ++mt){
#pragma unroll
        for (int nt = 0; nt < 2; ++nt){
            const int col = bcol0 + wc * 64 + nt * 32 + (lane & 31);
            const float c2v = g_c2[col];
#pragma unroll
            for (int reg = 0; reg < 16; ++reg){
                const int row = brow0 + wr * 64 + mt * 32 + (reg & 3) + 8 * (reg >> 2) + 4 * kh;
                float d2 = g_f2[row] + c2v - 2.0f * acc[mt][nt][reg];
                float d  = sqrtf(fmaxf(d2, 0.0f));
                float e32 = __expf(-2.0f * d) * 8192.0f;
                size_t idx = (size_t)row * NK + col;
                h16 hv; hv.h = (_Float16)e32;
                float hf = (float)hv.h;
                h16 rv; rv.h = (_Float16)(e32 - hf);
                g_E[idx] = hv.u;
                g_R[idx] = rv.u;
            }
        }
    }
}

// ---------------- fused sinkhorn sweep (+ in-block partial reduction) ----------------
// k-map (all modes): k = 512j + 8*lane + c   (16B ushort8 loads)
// tsum now split into 4 independent per-j accumulators (chain depth 32 -> 8);
// row loop explicitly unrolled so next row's loads hoist over current reduce.
template<int MODE>
__global__ __launch_bounds__(256) void cn_sweep(float* __restrict__ outba){
    __shared__ float4 sred[3][8][64];
    const int lane = threadIdx.x & 63, wid = threadIdx.x >> 6;
    const int row0 = (blockIdx.x * 4 + wid) * 4;
    const float cst = (MODE == 0) ? 1.0f : (1.0f / (float)NB);

    float4 uu[8];
    if (MODE >= 1){
#pragma unroll
        for (int j = 0; j < 4; ++j)
#pragma unroll
            for (int h = 0; h < 2; ++h)
                uu[2 * j + h] = *(const float4*)&g_u[512 * j + 8 * lane + 4 * h];
    }

    float4 S[8];
#pragma unroll
    for (int j = 0; j < 8; ++j) S[j] = make_float4(0.f,0.f,0.f,0.f);

#pragma unroll
    for (int r = 0; r < 4; ++r){
        const int b = row0 + r;
        float tt[4] = {0.f, 0.f, 0.f, 0.f};
        if (MODE <= 1){
            ushort8_t q8[4];
            const ushort* er = g_E + (size_t)b * NK + 8 * lane;
#pragma unroll
            for (int j = 0; j < 4; ++j){
                q8[j] = *(const ushort8_t*)(er + 512 * j);
#pragma unroll
                for (int c = 0; c < 8; ++c){
                    h16 cv; cv.u = q8[j][c];
                    float e = (float)cv.h;
                    tt[j] += (MODE == 1) ? e * (&uu[2 * j + (c >> 2)].x)[c & 3] : e;
                }
            }
            float tsum = (tt[0] + tt[1]) + (tt[2] + tt[3]);
#pragma unroll
            for (int off = 32; off; off >>= 1) tsum += __shfl_xor(tsum, off);
            const float v = cst / tsum;
#pragma unroll
            for (int j = 0; j < 4; ++j)
#pragma unroll
                for (int c = 0; c < 8; ++c){
                    h16 cv; cv.u = q8[j][c];
                    (&S[2 * j + (c >> 2)].x)[c & 3] += (float)cv.h * v;
                }
        } else {
            float ev[4][8];
            const ushort* er = g_E + (size_t)b * NK + 8 * lane;
            const ushort* rr = g_R + (size_t)b * NK + 8 * lane;
#pragma unroll
            for (int j = 0; j < 4; ++j){
                ushort8_t qe = *(const ushort8_t*)(er + 512 * j);
                ushort8_t qr = *(const ushort8_t*)(rr + 512 * j);
#pragma unroll
                for (int c = 0; c < 8; ++c){
                    h16 cv; cv.u = qe[c];
                    h16 rv; rv.u = qr[c];
                    float e = (float)cv.h + (float)rv.h;
                    ev[j][c] = e;
                    tt[j] += e * (&uu[2 * j + (c >> 2)].x)[c & 3];
                }
            }
            float tsum = (tt[0] + tt[1]) + (tt[2] + tt[3]);
#pragma unroll
            for (int off = 32; off; off >>= 1) tsum += __shfl_xor(tsum, off);
            const float v = cst / tsum;
#pragma unroll
            for (int j = 0; j < 4; ++j)
#pragma unroll
                for (int c = 0; c < 8; ++c)
                    (&S[2 * j + (c >> 2)].x)[c & 3] += ev[j][c] * v;

            if (MODE == 3){
                double bestW = 1.0e300; int bi = 0; float be = 1.f;
                float rbe = -1.f;      int ri = 0;
#pragma unroll
                for (int j = 0; j < 4; ++j){
#pragma unroll
                    for (int c = 0; c < 8; ++c){
                        int k = 512 * j + 8 * lane + c;
                        float e = ev[j][c];
                        double w = (double)e * (double)(&uu[2 * j + (c >> 2)].x)[c & 3];
                        if (w < bestW){ bestW = w; bi = k; be = e; }
                        if (e > rbe){ rbe = e; ri = k; }
                    }
                }
                for (int off = 32; off; off >>= 1){
                    double oW = __shfl_xor(bestW, off);
                    int    oi = __shfl_xor(bi, off);
                    float  oe = __shfl_xor(be, off);
                    if (oW < bestW || (oW == bestW && oi < bi)){ bestW = oW; bi = oi; be = oe; }
                    float ore = __shfl_xor(rbe, off);
                    int   ori = __shfl_xor(ri, off);
                    if (ore > rbe || (ore == rbe && ori < ri)){ rbe = ore; ri = ori; }
                }
                if (lane == 0){
                    outba[b] = (float)bi;
                    g_bd[b] = (float)(-0.5 * (log((double)be) - 9.010913347279288));
                    atomicAdd(&g_cc[bi], 1);
                    atomicAdd(&g_rc[ri], 1);
                }
            }
        }
    }

    if (wid > 0){
#pragma unroll
        for (int j = 0; j < 8; ++j) sred[wid - 1][j][lane] = S[j];
    }
    __syncthreads();
    if (wid == 0){
#pragma unroll
        for (int w = 0; w < 3; ++w)
#pragma unroll
            for (int j = 0; j < 8; ++j){
                float4 o = sred[w][j][lane];
                S[j].x += o.x; S[j].y += o.y; S[j].z += o.z; S[j].w += o.w;
            }
#pragma unroll
        for (int j = 0; j < 4; ++j)
#pragma unroll
            for (int h = 0; h < 2; ++h)
                *(float4*)&g_part[(size_t)blockIdx.x * NK + 512 * j + 8 * lane + 4 * h] = S[2 * j + h];
    }
}

// ---------------- wide u-reduction: 256 blocks, 8 k/block, coalesced, fixed-order fp64 ----------------
__global__ __launch_bounds__(256) void cn_red0(){
    __shared__ double red[4][8];
    const int kk  = threadIdx.x & 7;
    const int sub = threadIdx.x >> 3;
    const int wv  = threadIdx.x >> 6;
    const int k = blockIdx.x * 8 + kk;
    double s = 0.0;
#pragma unroll 8
    for (int i = 0; i < 32; ++i)
        s += (double)g_part[(size_t)(i * 32 + sub) * NK + k];
    s += __shfl_xor(s, 8); s += __shfl_xor(s, 16); s += __shfl_xor(s, 32);
    if ((threadIdx.x & 63) < 8) red[wv][kk] = s;
    __syncthreads();
    if (threadIdx.x < 8){
        double tot = red[0][kk] + red[1][kk] + red[2][kk] + red[3][kk];
        g_u[blockIdx.x * 8 + kk] = (float)((1.0 / (double)NK) / tot);
    }
}

// ---------------- merged epilogue: scnt + cc/rc + deterministic fp64 loss ----------------
__global__ __launch_bounds__(256) void cn_fin(float* __restrict__ out){
    __shared__ double red[4][64];
    __shared__ double lred[4];
    const int lane = threadIdx.x & 63, q = threadIdx.x >> 6;
    const int k = blockIdx.x * 64 + lane;
    double s = 0.0;
    for (int ch = q * 256; ch < q * 256 + 256; ++ch)
        s += (double)g_part[(size_t)ch * NK + k];
    red[q][lane] = s;
    __syncthreads();
    if (q == 0){
        double tot = red[0][lane] + red[1][lane] + red[2][lane] + red[3][lane];
        out[1 + NB + k] = (float)((double)NB * (double)g_u[k] * tot);
    } else if (q == 1){
        out[1 + NB + NK + k] = (float)g_cc[k];
    } else if (q == 2){
        out[1 + NB + 2 * NK + k] = (float)g_rc[k];
    }
    if (blockIdx.x == 0){
        double sl = 0.0;
        for (int b = threadIdx.x; b < NB; b += 256) sl += (double)g_bd[b];
        for (int off = 32; off; off >>= 1) sl += __shfl_xor(sl, off);
        if (lane == 0) lred[q] = sl;
        __syncthreads();
        if (threadIdx.x == 0)
            out[0] = (float)((lred[0] + lred[1] + lred[2] + lred[3]) / (double)NB);
    }
}

extern "C" void kernel_launch(void* const* d_in, const int* in_sizes, int n_in,
                              void* d_out, int out_size, void* d_ws, size_t ws_size,
                              hipStream_t stream){
    const float* F  = (const float*)d_in[0];
    const float* Cn = (const float*)d_in[1];
    float* out = (float*)d_out;
    (void)d_ws; (void)ws_size;

    cn_prep<<<NB + NK, 256, 0, stream>>>(F, Cn);

    dim3 gg(NK / 128, NB / 128);
    cn_gemm_dist<<<gg, 256, 0, stream>>>();

    // it 0: fp16, u==1
    cn_sweep<0><<<NCHK, 256, 0, stream>>>(nullptr);
    cn_red0<<<NK / 8, 256, 0, stream>>>();
    // it 1..11: fp16
    for (int it = 1; it <= 11; ++it){
        cn_sweep<1><<<NCHK, 256, 0, stream>>>(nullptr);
        cn_red0<<<NK / 8, 256, 0, stream>>>();
    }
    // it 12..14: exact (E+R reconstruction) tail
    for (int it = 12; it <= 14; ++it){
        cn_sweep<2><<<NCHK, 256, 0, stream>>>(nullptr);
        cn_red0<<<NK / 8, 256, 0, stream>>>();
    }
    // final sweep: fused assign/argmin/loss; S(v_15) -> scnt partials
    cn_sweep<3><<<NCHK, 256, 0, stream>>>(out + 1);
    cn_fin<<<NK / 64, 256, 0, stream>>>(out);
}

// Round 20
// 698.183 us; speedup vs baseline: 1.0647x; 1.0647x over previous
//
#include <hip/hip_runtime.h>

typedef __attribute__((ext_vector_type(8))) short bf16x8;
typedef __attribute__((ext_vector_type(8))) unsigned short ushort8_t;
typedef __attribute__((ext_vector_type(4))) float f32x4;
typedef __attribute__((ext_vector_type(16))) float f32x16;

#define NB 16384
#define NK 2048
#define ND 1000
#define KP 1024            // padded K
#define NCHK 1024          // sinkhorn partial chunks (1 per sweep block)

__device__ ushort g_E[(size_t)NB * NK];             // 64 MiB fp16 e' = exp(-2d)*8192 (hi)
__device__ ushort g_R[(size_t)NB * NK];             // 64 MiB fp16 residual (e32 - hi)
__device__ ushort g_Fh[(size_t)NB * KP], g_Fl[(size_t)NB * KP];   // pre-swizzled (64k windows)
__device__ ushort g_Ch[(size_t)NK * KP], g_Cl[(size_t)NK * KP];
__device__ float  g_u[NK], g_c2[NK];
__device__ float  g_f2[NB], g_bd[NB];
__device__ float  g_part[(size_t)NCHK * NK];        // 8 MiB
__device__ int    g_cc[NK], g_rc[NK];

typedef const __attribute__((address_space(1))) void gvoid_t;
typedef __attribute__((address_space(3))) void lvoid_t;

union h16 { ushort u; _Float16 h; };

__device__ __forceinline__ ushort bf16_rne(float x){
    uint u = __float_as_uint(x);
    uint lsb = (u >> 16) & 1u;
    u += 0x7fffu + lsb;
    return (ushort)(u >> 16);
}
__device__ __forceinline__ float bf16_to_f(ushort h){
    return __uint_as_float(((uint)h) << 16);
}

// ---------------- prep (merged): fp32 -> (hi,lo) bf16 split, K-pad, row-sumsq ----------------
// Swizzle for BK=64 GEMM tiles: within each 64-col window (8 x 16B granules),
// granule g of row r is stored at g ^ (r & 7).
__global__ __launch_bounds__(256) void cn_prep(const float* __restrict__ F,
                                               const float* __restrict__ Cn){
    const int isC = (blockIdx.x >= NB);
    const int row = isC ? (blockIdx.x - NB) : blockIdx.x;
    const float* __restrict__ X = isC ? Cn : F;
    ushort* __restrict__ H = isC ? g_Ch : g_Fh;
    ushort* __restrict__ L = isC ? g_Cl : g_Fl;
    float*  __restrict__ sq = isC ? g_c2 : g_f2;
    const int t = threadIdx.x;
    const int lane = t & 63, wid = t >> 6;
    if (isC && t == 0){ g_cc[row] = 0; g_rc[row] = 0; }
    float4 x = make_float4(0.f,0.f,0.f,0.f);
    if (t < 250) x = *(const float4*)(X + (size_t)row * ND + 4 * t);
    double s = (double)x.x*x.x + (double)x.y*x.y + (double)x.z*x.z + (double)x.w*x.w;
    ushort4 h4, l4;
#pragma unroll
    for (int c = 0; c < 4; ++c){
        float xc = (&x.x)[c];
        ushort h = bf16_rne(xc);
        (&h4.x)[c] = h;
        (&l4.x)[c] = bf16_rne(xc - bf16_to_f(h));
    }
    const int base = (t >> 4) << 6;                 // 64-col window
    const int grp  = (t >> 1) & 7;                  // granule 0..7 within window
    const int pos  = base + ((grp ^ (row & 7)) << 3) + ((4 * t) & 7);
    *(ushort4*)&H[(size_t)row * KP + pos] = h4;
    *(ushort4*)&L[(size_t)row * KP + pos] = l4;

    __shared__ double pr[4];
    for (int off = 32; off; off >>= 1) s += __shfl_xor(s, off);
    if (lane == 0) pr[wid] = s;
    __syncthreads();
    if (t == 0) sq[row] = (float)(pr[0] + pr[1] + pr[2] + pr[3]);
}

// ---------------- split-bf16 32x32x16 MFMA distance GEMM, BK=64 single-buffer ----------------
// + T1 XCD-aware block swizzle: 2048 blocks -> 8 chunks of 256 contiguous tiles,
// so each XCD's L2 sees whole A-panels once (bijective: 2048 % 8 == 0).
__global__ __launch_bounds__(256) void cn_gemm_dist(){
    __shared__ __attribute__((aligned(16))) ushort Ah[128 * 64];
    __shared__ __attribute__((aligned(16))) ushort Al[128 * 64];
    __shared__ __attribute__((aligned(16))) ushort Bh[128 * 64];
    __shared__ __attribute__((aligned(16))) ushort Bl[128 * 64];

    const int tid = threadIdx.x;
    const int lane = tid & 63, wid = tid >> 6;
    const int wr = wid >> 1, wc = wid & 1;

    // XCD swizzle (m157 form): lin%8 ~ XCD; give each XCD 256 consecutive tiles.
    const int lin = blockIdx.y * gridDim.x + blockIdx.x;
    const int swz = (lin & 7) * 256 + (lin >> 3);
    const int brow0 = (swz >> 4) * 128;            // 128 y-panels
    const int bcol0 = (swz & 15) * 128;            // 16 x-tiles

    f32x16 acc[2][2];
#pragma unroll
    for (int mt = 0; mt < 2; ++mt)
#pragma unroll
        for (int nt = 0; nt < 2; ++nt)
#pragma unroll
            for (int r = 0; r < 16; ++r) acc[mt][nt][r] = 0.f;

    const int srow = lane >> 3;            // 0..7 row within 8-row chunk
    const int sgr  = lane & 7;             // granule within row

    const int arow = wr * 64 + (lane & 31);
    const int brow = wc * 64 + (lane & 31);
    const int kh   = lane >> 5;            // k-half (0/1)
    const int rx   = lane & 7;             // swizzle key (= row & 7)

    for (int kt = 0; kt < 16; ++kt){
        const int k0 = kt * 64;
#pragma unroll
        for (int c4 = 0; c4 < 4; ++c4){
            const int ch = wid * 4 + c4;           // 0..15
            const int ldso = ch * 512;             // ushorts (1 KB)
            const size_t ga = (size_t)(brow0 + ch * 8 + srow) * KP + k0 + sgr * 8;
            const size_t gb = (size_t)(bcol0 + ch * 8 + srow) * KP + k0 + sgr * 8;
            __builtin_amdgcn_global_load_lds((gvoid_t*)(g_Fh + ga), (lvoid_t*)(Ah + ldso), 16, 0, 0);
            __builtin_amdgcn_global_load_lds((gvoid_t*)(g_Fl + ga), (lvoid_t*)(Al + ldso), 16, 0, 0);
            __builtin_amdgcn_global_load_lds((gvoid_t*)(g_Ch + gb), (lvoid_t*)(Bh + ldso), 16, 0, 0);
            __builtin_amdgcn_global_load_lds((gvoid_t*)(g_Cl + gb), (lvoid_t*)(Bl + ldso), 16, 0, 0);
        }
        __syncthreads();

#pragma unroll
        for (int ks = 0; ks < 4; ++ks){
            const int pg = (ks * 2 + kh) ^ rx;     // physical granule (swizzled)
            bf16x8 a_h[2], a_l[2], b_h[2], b_l[2];
#pragma unroll
            for (int mt = 0; mt < 2; ++mt){
                const int ro = (arow + mt * 32) * 64 + pg * 8;
                a_h[mt] = *(const bf16x8*)&Ah[ro];
                a_l[mt] = *(const bf16x8*)&Al[ro];
            }
#pragma unroll
            for (int nt = 0; nt < 2; ++nt){
                const int ro = (brow + nt * 32) * 64 + pg * 8;
                b_h[nt] = *(const bf16x8*)&Bh[ro];
                b_l[nt] = *(const bf16x8*)&Bl[ro];
            }
#pragma unroll
            for (int mt = 0; mt < 2; ++mt)
#pragma unroll
                for (int nt = 0; nt < 2; ++nt){
                    acc[mt][nt] = __builtin_amdgcn_mfma_f32_32x32x16_bf16(a_h[mt], b_h[nt], acc[mt][nt], 0, 0, 0);
                    acc[mt][nt] = __builtin_amdgcn_mfma_f32_32x32x16_bf16(a_h[mt], b_l[nt], acc[mt][nt], 0, 0, 0);
                    acc[mt][nt] = __builtin_amdgcn_mfma_f32_32x32x16_bf16(a_l[mt], b_h[nt], acc[mt][nt], 0, 0, 0);
                }
        }
        __syncthreads();
    }

    // epilogue: C layout (32x32): col = lane&31, row = (reg&3) + 8*(reg>>2) + 4*(lane>>5)
#pragma unroll
    for (int mt = 0; mt < 2; ++mt){
#pragma unroll
        for (int nt = 0; nt < 2; ++nt){
            const int col = bcol0 + wc * 64 + nt * 32 + (lane & 31);
            const float c2v = g_c2[col];
#pragma unroll
            for (int reg = 0; reg < 16; ++reg){
                const int row = brow0 + wr * 64 + mt * 32 + (reg & 3) + 8 * (reg >> 2) + 4 * kh;
                float d2 = g_f2[row] + c2v - 2.0f * acc[mt][nt][reg];
                float d  = sqrtf(fmaxf(d2, 0.0f));
                float e32 = __expf(-2.0f * d) * 8192.0f;
                size_t idx = (size_t)row * NK + col;
                h16 hv; hv.h = (_Float16)e32;
                float hf = (float)hv.h;
                h16 rv; rv.h = (_Float16)(e32 - hf);
                g_E[idx] = hv.u;
                g_R[idx] = rv.u;
            }
        }
    }
}

// ---------------- fused sinkhorn sweep (+ in-block partial reduction) ----------------
// k-map (all modes): k = 512j + 8*lane + c   (16B ushort8 loads)
// MODE 0: fp16-e first sweep (u==1):  v = 1/T
// MODE 1: fp16-e mid sweep:           v = (1/B)/T,  T = sum e*u
// MODE 2: exact mid sweep: e = h + r  (fp32-class reconstruction)
// MODE 3: exact final + argmin(e*u) [= argmax t], argmax e [= argmin d], bd, histograms
template<int MODE>
__global__ __launch_bounds__(256) void cn_sweep(float* __restrict__ outba){
    __shared__ float4 sred[3][8][64];
    const int lane = threadIdx.x & 63, wid = threadIdx.x >> 6;
    const int row0 = (blockIdx.x * 4 + wid) * 4;
    const float cst = (MODE == 0) ? 1.0f : (1.0f / (float)NB);

    float4 uu[8];
    if (MODE >= 1){
#pragma unroll
        for (int j = 0; j < 4; ++j)
#pragma unroll
            for (int h = 0; h < 2; ++h)
                uu[2 * j + h] = *(const float4*)&g_u[512 * j + 8 * lane + 4 * h];
    }

    float4 S[8];
#pragma unroll
    for (int j = 0; j < 8; ++j) S[j] = make_float4(0.f,0.f,0.f,0.f);

    for (int r = 0; r < 4; ++r){
        const int b = row0 + r;
        float tsum = 0.f;
        if (MODE <= 1){
            ushort8_t q8[4];
            const ushort* er = g_E + (size_t)b * NK + 8 * lane;
#pragma unroll
            for (int j = 0; j < 4; ++j){
                q8[j] = *(const ushort8_t*)(er + 512 * j);
#pragma unroll
                for (int c = 0; c < 8; ++c){
                    h16 cv; cv.u = q8[j][c];
                    float e = (float)cv.h;
                    tsum += (MODE == 1) ? e * (&uu[2 * j + (c >> 2)].x)[c & 3] : e;
                }
            }
#pragma unroll
            for (int off = 32; off; off >>= 1) tsum += __shfl_xor(tsum, off);
            const float v = cst / tsum;
#pragma unroll
            for (int j = 0; j < 4; ++j)
#pragma unroll
                for (int c = 0; c < 8; ++c){
                    h16 cv; cv.u = q8[j][c];
                    (&S[2 * j + (c >> 2)].x)[c & 3] += (float)cv.h * v;
                }
        } else {
            float ev[4][8];
            const ushort* er = g_E + (size_t)b * NK + 8 * lane;
            const ushort* rr = g_R + (size_t)b * NK + 8 * lane;
#pragma unroll
            for (int j = 0; j < 4; ++j){
                ushort8_t qe = *(const ushort8_t*)(er + 512 * j);
                ushort8_t qr = *(const ushort8_t*)(rr + 512 * j);
#pragma unroll
                for (int c = 0; c < 8; ++c){
                    h16 cv; cv.u = qe[c];
                    h16 rv; rv.u = qr[c];
                    float e = (float)cv.h + (float)rv.h;
                    ev[j][c] = e;
                    tsum += e * (&uu[2 * j + (c >> 2)].x)[c & 3];
                }
            }
#pragma unroll
            for (int off = 32; off; off >>= 1) tsum += __shfl_xor(tsum, off);
            const float v = cst / tsum;
#pragma unroll
            for (int j = 0; j < 4; ++j)
#pragma unroll
                for (int c = 0; c < 8; ++c)
                    (&S[2 * j + (c >> 2)].x)[c & 3] += ev[j][c] * v;

            if (MODE == 3){
                double bestW = 1.0e300; int bi = 0; float be = 1.f;
                float rbe = -1.f;      int ri = 0;
#pragma unroll
                for (int j = 0; j < 4; ++j){
#pragma unroll
                    for (int c = 0; c < 8; ++c){
                        int k = 512 * j + 8 * lane + c;
                        float e = ev[j][c];
                        double w = (double)e * (double)(&uu[2 * j + (c >> 2)].x)[c & 3];
                        if (w < bestW){ bestW = w; bi = k; be = e; }
                        if (e > rbe){ rbe = e; ri = k; }
                    }
                }
                for (int off = 32; off; off >>= 1){
                    double oW = __shfl_xor(bestW, off);
                    int    oi = __shfl_xor(bi, off);
                    float  oe = __shfl_xor(be, off);
                    if (oW < bestW || (oW == bestW && oi < bi)){ bestW = oW; bi = oi; be = oe; }
                    float ore = __shfl_xor(rbe, off);
                    int   ori = __shfl_xor(ri, off);
                    if (ore > rbe || (ore == rbe && ori < ri)){ rbe = ore; ri = ori; }
                }
                if (lane == 0){
                    outba[b] = (float)bi;
                    g_bd[b] = (float)(-0.5 * (log((double)be) - 9.010913347279288));
                    atomicAdd(&g_cc[bi], 1);
                    atomicAdd(&g_rc[ri], 1);
                }
            }
        }
    }

    if (wid > 0){
#pragma unroll
        for (int j = 0; j < 8; ++j) sred[wid - 1][j][lane] = S[j];
    }
    __syncthreads();
    if (wid == 0){
#pragma unroll
        for (int w = 0; w < 3; ++w)
#pragma unroll
            for (int j = 0; j < 8; ++j){
                float4 o = sred[w][j][lane];
                S[j].x += o.x; S[j].y += o.y; S[j].z += o.z; S[j].w += o.w;
            }
#pragma unroll
        for (int j = 0; j < 4; ++j)
#pragma unroll
            for (int h = 0; h < 2; ++h)
                *(float4*)&g_part[(size_t)blockIdx.x * NK + 512 * j + 8 * lane + 4 * h] = S[2 * j + h];
    }
}

// ---------------- wide u-reduction: 256 blocks, 8 k/block, coalesced, fixed-order fp64 ----------------
__global__ __launch_bounds__(256) void cn_red0(){
    __shared__ double red[4][8];
    const int kk  = threadIdx.x & 7;
    const int sub = threadIdx.x >> 3;
    const int wv  = threadIdx.x >> 6;
    const int k = blockIdx.x * 8 + kk;
    double s = 0.0;
#pragma unroll 8
    for (int i = 0; i < 32; ++i)
        s += (double)g_part[(size_t)(i * 32 + sub) * NK + k];
    s += __shfl_xor(s, 8); s += __shfl_xor(s, 16); s += __shfl_xor(s, 32);
    if ((threadIdx.x & 63) < 8) red[wv][kk] = s;
    __syncthreads();
    if (threadIdx.x < 8){
        double tot = red[0][kk] + red[1][kk] + red[2][kk] + red[3][kk];
        g_u[blockIdx.x * 8 + kk] = (float)((1.0 / (double)NK) / tot);
    }
}

// ---------------- merged epilogue: scnt + cc/rc + deterministic fp64 loss ----------------
__global__ __launch_bounds__(256) void cn_fin(float* __restrict__ out){
    __shared__ double red[4][64];
    __shared__ double lred[4];
    const int lane = threadIdx.x & 63, q = threadIdx.x >> 6;
    const int k = blockIdx.x * 64 + lane;
    double s = 0.0;
    for (int ch = q * 256; ch < q * 256 + 256; ++ch)
        s += (double)g_part[(size_t)ch * NK + k];
    red[q][lane] = s;
    __syncthreads();
    if (q == 0){
        double tot = red[0][lane] + red[1][lane] + red[2][lane] + red[3][lane];
        out[1 + NB + k] = (float)((double)NB * (double)g_u[k] * tot);
    } else if (q == 1){
        out[1 + NB + NK + k] = (float)g_cc[k];
    } else if (q == 2){
        out[1 + NB + 2 * NK + k] = (float)g_rc[k];
    }
    if (blockIdx.x == 0){
        double sl = 0.0;
        for (int b = threadIdx.x; b < NB; b += 256) sl += (double)g_bd[b];
        for (int off = 32; off; off >>= 1) sl += __shfl_xor(sl, off);
        if (lane == 0) lred[q] = sl;
        __syncthreads();
        if (threadIdx.x == 0)
            out[0] = (float)((lred[0] + lred[1] + lred[2] + lred[3]) / (double)NB);
    }
}

extern "C" void kernel_launch(void* const* d_in, const int* in_sizes, int n_in,
                              void* d_out, int out_size, void* d_ws, size_t ws_size,
                              hipStream_t stream){
    const float* F  = (const float*)d_in[0];
    const float* Cn = (const float*)d_in[1];
    float* out = (float*)d_out;
    (void)d_ws; (void)ws_size;

    cn_prep<<<NB + NK, 256, 0, stream>>>(F, Cn);

    dim3 gg(NK / 128, NB / 128);
    cn_gemm_dist<<<gg, 256, 0, stream>>>();

    // it 0: fp16, u==1
    cn_sweep<0><<<NCHK, 256, 0, stream>>>(nullptr);
    cn_red0<<<NK / 8, 256, 0, stream>>>();
    // it 1..11: fp16
    for (int it = 1; it <= 11; ++it){
        cn_sweep<1><<<NCHK, 256, 0, stream>>>(nullptr);
        cn_red0<<<NK / 8, 256, 0, stream>>>();
    }
    // it 12..14: exact (E+R reconstruction) tail
    for (int it = 12; it <= 14; ++it){
        cn_sweep<2><<<NCHK, 256, 0, stream>>>(nullptr);
        cn_red0<<<NK / 8, 256, 0, stream>>>();
    }
    // final sweep: fused assign/argmin/loss; S(v_15) -> scnt partials
    cn_sweep<3><<<NCHK, 256, 0, stream>>>(out + 1);
    cn_fin<<<NK / 64, 256, 0, stream>>>(out);
}